// Round 12
// baseline (105.577 us; speedup 1.0000x reference)
//
#include <hip/hip_runtime.h>
#include <stdint.h>

#define B_TOT 2048
#define H_DIM 4096
#define R_DIM 64
#define NA_DIM 64
#define GS 16
#define X_ELEMS (B_TOT*H_DIM)        // 8388608
#define W_ELEMS (B_TOT)              // 2048
#define A_ELEMS (NA_DIM*H_DIM*R_DIM) // 16777216

// Block (adapter a, k-slice ks): 4 waves, k in [ks*KS, (ks+1)*KS).
// A streams from global fully coalesced (dwordx4/lane = 1 KB/wave per 4-k
// iter, depth-2 register prefetch, zero reuse so no staging). x staged in
// LDS [s][k] (XPAD word padding; staging writes cover 64 consecutive words
// per 16-lane group -> conflict-free). Inner loop barrier-free; lane
// (lg = l>>4 picks k-sub, rq = l&15 picks r-quad) holds acc[16][4] (~64
// VGPR -- NO waves-per-EU cap, spills are worse than occupancy here).
// Epilogue per group: shfl_xor butterfly over lg + cross-wave LDS reduce,
// f32 partial slice -> ws. k_reduceN sums the NS slices.
template<int NS>
__global__ __launch_bounds__(256)
void k_lora_stream(const float* __restrict__ x, const int* __restrict__ wids,
                   const float* __restrict__ A, float* __restrict__ part) {
  constexpr int KS = H_DIM / NS;     // 256 (NS=16) / 512 (NS=8)
  constexpr int XPAD = KS + 4;
  constexpr int RSN = 4 * 16 * 68;   // 4352 f32 reduce scratch (aliases XT)
  constexpr int POOLN = (GS * XPAD > RSN ? GS * XPAD : RSN);
  __shared__ __align__(16) float POOL[POOLN];
  __shared__ uint16_t sbin[B_TOT];   // 4 KB ordered sample list
  __shared__ int sn;

  const int bx = blockIdx.x;
  const int a = bx / NS, ks = bx % NS;
  const int t = threadIdx.x;
  const int w = t >> 6, l = t & 63;

  // ---- wave 0: ballot-scan wids -> ordered bin list (deterministic) ----
  if (w == 0) {
    int v[32];
#pragma unroll
    for (int i = 0; i < 32; ++i) v[i] = wids[i * 64 + l];
    int cnt = 0;
#pragma unroll
    for (int i = 0; i < 32; ++i) {
      bool hit = (v[i] == a);
      unsigned long long m = __ballot(hit);
      if (hit) sbin[cnt + __popcll(m & ((1ull << l) - 1ull))] = (uint16_t)(i * 64 + l);
      cnt += __popcll(m);
    }
    if (l == 0) sn = cnt;
  }
  __syncthreads();
  const int n = sn;
  if (n == 0) return;

  const int rq = l & 15;             // r-quad: r = 4rq..4rq+3
  const int lg = l >> 4;             // k-sub within 4-row A load
  const int s_st = t >> 4, q_st = t & 15;   // staging roles
  const int wkb = w * (KS / 4);      // wave k-base within slice
  constexpr int NIT = KS / 16;       // 4-k iters per wave

  const float* Aslice = A + ((size_t)a * H_DIM + (size_t)ks * KS) * R_DIM;
  const float* Agl = Aslice + (size_t)wkb * R_DIM + l * 4;  // lane A stream base

  for (int g = 0; g * GS < n; ++g) {
    const int base = g * GS;
    __syncthreads();   // POOL free (prev group's epilogue reads done)

    // ---- stage x tile [s][k]: lane group covers 64 consecutive words ----
    {
      int sidx = base + s_st; if (sidx > n - 1) sidx = n - 1;
      const float* xr = x + (size_t)sbin[sidx] * H_DIM + (size_t)ks * KS;
      float* xd = POOL + s_st * XPAD;
#pragma unroll
      for (int i = 0; i < KS / 64; ++i) {
        int o = q_st * 4 + i * 64;
        *(float4*)(xd + o) = *(const float4*)(xr + o);
      }
    }
    __syncthreads();   // XT ready

    // ---- barrier-free compute: stream A, depth-2 prefetch ----
    float acc[GS][4];
#pragma unroll
    for (int s = 0; s < GS; ++s)
#pragma unroll
      for (int c = 0; c < 4; ++c) acc[s][c] = 0.f;

    float4 a_cur = *(const float4*)(Agl);
    float4 a_nxt = *(const float4*)(Agl + 256);
    const float* xbase = POOL + wkb + lg;
#pragma unroll 2
    for (int it = 0; it < NIT; ++it) {
      const int pfi = (it + 2 < NIT) ? (it + 2) : 0;
      float4 a_pf = *(const float4*)(Agl + (size_t)pfi * 256);
      const float* xb = xbase + it * 4;
#pragma unroll
      for (int s = 0; s < GS; ++s) {
        float xs = xb[s * XPAD];   // ds_read_b32, 16-lane broadcast x 4 banks
        acc[s][0] += xs * a_cur.x; acc[s][1] += xs * a_cur.y;
        acc[s][2] += xs * a_cur.z; acc[s][3] += xs * a_cur.w;
      }
      a_cur = a_nxt; a_nxt = a_pf;
    }

    // ---- intra-wave k-reduce (over lg) via 2-step butterfly ----
#pragma unroll
    for (int s = 0; s < GS; ++s)
#pragma unroll
      for (int c = 0; c < 4; ++c) {
        float v = acc[s][c];
        v += __shfl_xor(v, 16);
        v += __shfl_xor(v, 32);
        acc[s][c] = v;
      }

    __syncthreads();   // all XT reads done -> POOL reusable as RS
    // RS[w][16][68]: lane (lg,rq) writes s = lg*4..lg*4+3
    {
      float* rs = POOL + w * 1088;
#pragma unroll
      for (int j = 0; j < 4; ++j) {
        int s = lg * 4 + j;
        *(float4*)(rs + s * 68 + rq * 4) =
            make_float4(acc[s][0], acc[s][1], acc[s][2], acc[s][3]);
      }
    }
    __syncthreads();   // RS ready

    // ---- final: thread (fs, frq) sums 4 waves, writes partial slice ----
    {
      int fs = t >> 4, frq = t & 15;
      int sidx = base + fs;
      if (sidx < n) {
        float4 s0 = *(const float4*)(POOL + 0 * 1088 + fs * 68 + frq * 4);
        float4 s1 = *(const float4*)(POOL + 1 * 1088 + fs * 68 + frq * 4);
        float4 s2 = *(const float4*)(POOL + 2 * 1088 + fs * 68 + frq * 4);
        float4 s3 = *(const float4*)(POOL + 3 * 1088 + fs * 68 + frq * 4);
        float4 r = make_float4(s0.x + s1.x + s2.x + s3.x,
                               s0.y + s1.y + s2.y + s3.y,
                               s0.z + s1.z + s2.z + s3.z,
                               s0.w + s1.w + s2.w + s3.w);
        *(float4*)&part[(size_t)ks * (B_TOT * R_DIM) +
                        (size_t)sbin[sidx] * R_DIM + frq * 4] = r;
      }
    }
  }
}

template<int NS>
__global__ __launch_bounds__(256)
void k_reduceN(const float* __restrict__ part, float* __restrict__ out) {
  int t = blockIdx.x * 256 + threadIdx.x;   // 32768 threads, one float4 each
  size_t o = (size_t)t * 4;
  float v0 = 0.f, v1 = 0.f, v2 = 0.f, v3 = 0.f;
#pragma unroll
  for (int p = 0; p < NS; ++p) {
    float4 q = *(const float4*)&part[(size_t)p * (B_TOT * R_DIM) + o];
    v0 += q.x; v1 += q.y; v2 += q.z; v3 += q.w;
  }
  *(float4*)&out[o] = make_float4(v0, v1, v2, v3);
}

// No-workspace fallback (proven-correct round-6 naive kernel).
__global__ __launch_bounds__(256)
void k_naive_f32(const float* __restrict__ x, const int* __restrict__ wids,
                 const float* __restrict__ A, float* __restrict__ out) {
  __shared__ float red[256];
  const int b = blockIdx.x;
  const int t = threadIdx.x;
  const int r = t & 63;
  const int q = t >> 6;
  const int a = wids[b];
  const float* xrow = x + (size_t)b * H_DIM;
  const float* Aad  = A + (size_t)a * H_DIM * R_DIM + r;
  float acc = 0.f;
  const int h0 = q * (H_DIM / 4), h1 = h0 + (H_DIM / 4);
  for (int h = h0; h < h1; ++h) acc += xrow[h] * Aad[(size_t)h * R_DIM];
  red[t] = acc;
  __syncthreads();
  if (t < 64) {
    out[(size_t)b * R_DIM + t] = red[t] + red[t + 64] + red[t + 128] + red[t + 192];
  }
}

extern "C" void kernel_launch(void* const* d_in, const int* in_sizes, int n_in,
                              void* d_out, int out_size, void* d_ws, size_t ws_size,
                              hipStream_t stream) {
  // Identify inputs by element count — robust to any ordering.
  const void* px = nullptr; const void* pw = nullptr; const void* pa = nullptr;
  for (int i = 0; i < n_in; ++i) {
    if (in_sizes[i] == X_ELEMS) px = d_in[i];
    else if (in_sizes[i] == W_ELEMS) pw = d_in[i];
    else if (in_sizes[i] == A_ELEMS) pa = d_in[i];
  }
  if (!px || !pw || !pa) { px = d_in[0]; pw = d_in[1]; pa = d_in[2]; }

  const float* x    = (const float*)px;
  const int*   wids = (const int*)pw;
  const float* A    = (const float*)pa;
  float* out = (float*)d_out;
  (void)out_size;

  const size_t need16 = (size_t)16 * B_TOT * R_DIM * sizeof(float);  // 8 MB (proven fits, round 10)
  const size_t need8  = (size_t)8  * B_TOT * R_DIM * sizeof(float);  // 4 MB
  float* part = (float*)d_ws;
  if (ws_size >= need16) {
    k_lora_stream<16><<<dim3(NA_DIM * 16), dim3(256), 0, stream>>>(x, wids, A, part);
    k_reduceN<16><<<dim3(128), dim3(256), 0, stream>>>(part, out);
  } else if (ws_size >= need8) {
    k_lora_stream<8><<<dim3(NA_DIM * 8), dim3(256), 0, stream>>>(x, wids, A, part);
    k_reduceN<8><<<dim3(128), dim3(256), 0, stream>>>(part, out);
  } else {
    k_naive_f32<<<dim3(B_TOT), dim3(256), 0, stream>>>(x, wids, A, out);
  }
}

// Round 13
// 27.788 us; speedup vs baseline: 3.7994x; 3.7994x over previous
//
#include <hip/hip_runtime.h>
#include <stdint.h>

#define B_TOT 2048
#define H_DIM 4096
#define R_DIM 64
#define NA_DIM 64
#define NS 16                    // k-slices
#define KS (H_DIM / NS)          // 256 k per slice
#define LW 132                   // LDS row stride in u32 words (=264 f16), %32=4
#define X_ELEMS (B_TOT*H_DIM)
#define W_ELEMS (B_TOT)
#define A_ELEMS (NA_DIM*H_DIM*R_DIM)

typedef _Float16 f16x8 __attribute__((ext_vector_type(8)));
typedef float    f32x4 __attribute__((ext_vector_type(4)));

__device__ __forceinline__ uint32_t pkf16(float a, float b) {
  // exact: inputs are fp16-representable, RTZ == RNE == identity
  auto h = __builtin_amdgcn_cvt_pkrtz(a, b);
  union { decltype(h) v; uint32_t u; } cv; cv.v = h; return cv.u;
}

// Block (adapter a, k-slice ks): GEMM  X_a[n x 256] @ A_a[256 x 64] -> part[ks].
// A-slice staged once, transposed, f16: A_lds[r][k] (u32 = 2 f16 along k).
// Per 16-sample M-group: x staged f16 X_lds[m][k]; wave w owns n-cols
// w*16..w*16+15; 8 x mfma_f32_16x16x32_f16 per group; C/D map col=l&15,
// row=(l>>4)*4+i drives guarded f32 stores. Frag reads use the SAME
// (lane,elem)->k map for both operands (k-permutation-safe).
__global__ __launch_bounds__(256)
void k_lora_mfma(const float* __restrict__ x, const int* __restrict__ wids,
                 const float* __restrict__ A, float* __restrict__ part) {
  __shared__ __align__(16) uint32_t A_lds[R_DIM * LW];  // 33 KB
  __shared__ __align__(16) uint32_t X_lds[16 * LW];     // 8.25 KB
  __shared__ uint16_t sbin[B_TOT];                      // 4 KB
  __shared__ int sn;

  const int bx = blockIdx.x;
  const int a = bx / NS, ks = bx % NS;
  const int t = threadIdx.x;
  const int w = t >> 6, l = t & 63;

  // ---- stage A-slice: read [k][r] f32 coalesced, write [r][k] f16 ----
  {
    const float* Ab = A + ((size_t)a * H_DIM + (size_t)ks * KS) * R_DIM;
    const int kp = t >> 4, rc = t & 15;
#pragma unroll
    for (int p = 0; p < 8; ++p) {
      const int k = (p * 16 + kp) * 2;          // even k row
      float4 v0 = *(const float4*)(Ab + (size_t)k * R_DIM + rc * 4);
      float4 v1 = *(const float4*)(Ab + (size_t)(k + 1) * R_DIM + rc * 4);
      const int kk = k >> 1;
      A_lds[(rc * 4 + 0) * LW + kk] = pkf16(v0.x, v1.x);
      A_lds[(rc * 4 + 1) * LW + kk] = pkf16(v0.y, v1.y);
      A_lds[(rc * 4 + 2) * LW + kk] = pkf16(v0.z, v1.z);
      A_lds[(rc * 4 + 3) * LW + kk] = pkf16(v0.w, v1.w);
    }
  }

  // ---- wave 0: ballot-scan wids -> ordered sample list ----
  if (w == 0) {
    int v[32];
#pragma unroll
    for (int i = 0; i < 32; ++i) v[i] = wids[i * 64 + l];
    int cnt = 0;
#pragma unroll
    for (int i = 0; i < 32; ++i) {
      bool hit = (v[i] == a);
      unsigned long long m = __ballot(hit);
      if (hit) sbin[cnt + __popcll(m & ((1ull << l) - 1ull))] = (uint16_t)(i * 64 + l);
      cnt += __popcll(m);
    }
    if (l == 0) sn = cnt;
  }
  __syncthreads();   // A_lds + sbin ready
  const int n = sn;
  if (n == 0) return;

  const int ml = l & 15;    // X-row / D-col lane index
  const int kg = l >> 4;    // k-group
  const int m_st = t >> 4, q_st = t & 15;   // X staging roles

  for (int mg = 0; mg * 16 < n; ++mg) {
    const int base = mg * 16;
    // ---- stage x: 16 rows x 256 k -> f16 [m][k] ----
    {
      int sidx = base + m_st; if (sidx > n - 1) sidx = n - 1;
      const float* xr = x + (size_t)sbin[sidx] * H_DIM + (size_t)ks * KS;
#pragma unroll
      for (int j = 0; j < 2; ++j) {
        const int c = q_st + j * 16;          // 8-elem chunk id
        const int k = c * 8;
        float4 u0 = *(const float4*)(xr + k);
        float4 u1 = *(const float4*)(xr + k + 4);
        uint4 pw;
        pw.x = pkf16(u0.x, u0.y); pw.y = pkf16(u0.z, u0.w);
        pw.z = pkf16(u1.x, u1.y); pw.w = pkf16(u1.z, u1.w);
        *(uint4*)&X_lds[m_st * LW + c * 4] = pw;
      }
    }
    __syncthreads();   // X ready

    // ---- compute: wave w owns n-cols [w*16, w*16+16) ----
    f32x4 acc = {0.f, 0.f, 0.f, 0.f};
#pragma unroll
    for (int kst = 0; kst < 8; ++kst) {
      f16x8 xf = *(const f16x8*)(X_lds + ml * LW + kst * 16 + kg * 4);
      f16x8 af = *(const f16x8*)(A_lds + (w * 16 + ml) * LW + kst * 16 + kg * 4);
      acc = __builtin_amdgcn_mfma_f32_16x16x32_f16(xf, af, acc, 0, 0, 0);
    }

    // ---- store: D col = l&15 (-> r), row = kg*4+i (-> sample) ----
#pragma unroll
    for (int i = 0; i < 4; ++i) {
      const int mr = kg * 4 + i;
      const int sidx = base + mr;
      if (sidx < n) {
        part[(size_t)ks * (B_TOT * R_DIM) +
             (size_t)sbin[sidx] * R_DIM + w * 16 + ml] = acc[i];
      }
    }
    if ((mg + 1) * 16 < n) __syncthreads();   // X_lds reads done before restage
  }
}

__global__ __launch_bounds__(256)
void k_reduce16(const float* __restrict__ part, float* __restrict__ out) {
  int t = blockIdx.x * 256 + threadIdx.x;   // 32768 threads, one float4 each
  size_t o = (size_t)t * 4;
  float v0 = 0.f, v1 = 0.f, v2 = 0.f, v3 = 0.f;
#pragma unroll
  for (int p = 0; p < NS; ++p) {
    float4 q = *(const float4*)&part[(size_t)p * (B_TOT * R_DIM) + o];
    v0 += q.x; v1 += q.y; v2 += q.z; v3 += q.w;
  }
  *(float4*)&out[o] = make_float4(v0, v1, v2, v3);
}

// No-workspace fallback (proven-correct round-6 naive kernel).
__global__ __launch_bounds__(256)
void k_naive_f32(const float* __restrict__ x, const int* __restrict__ wids,
                 const float* __restrict__ A, float* __restrict__ out) {
  __shared__ float red[256];
  const int b = blockIdx.x;
  const int t = threadIdx.x;
  const int r = t & 63;
  const int q = t >> 6;
  const int a = wids[b];
  const float* xrow = x + (size_t)b * H_DIM;
  const float* Aad  = A + (size_t)a * H_DIM * R_DIM + r;
  float acc = 0.f;
  const int h0 = q * (H_DIM / 4), h1 = h0 + (H_DIM / 4);
  for (int h = h0; h < h1; ++h) acc += xrow[h] * Aad[(size_t)h * R_DIM];
  red[t] = acc;
  __syncthreads();
  if (t < 64) {
    out[(size_t)b * R_DIM + t] = red[t] + red[t + 64] + red[t + 128] + red[t + 192];
  }
}

extern "C" void kernel_launch(void* const* d_in, const int* in_sizes, int n_in,
                              void* d_out, int out_size, void* d_ws, size_t ws_size,
                              hipStream_t stream) {
  // Identify inputs by element count — robust to any ordering.
  const void* px = nullptr; const void* pw = nullptr; const void* pa = nullptr;
  for (int i = 0; i < n_in; ++i) {
    if (in_sizes[i] == X_ELEMS) px = d_in[i];
    else if (in_sizes[i] == W_ELEMS) pw = d_in[i];
    else if (in_sizes[i] == A_ELEMS) pa = d_in[i];
  }
  if (!px || !pw || !pa) { px = d_in[0]; pw = d_in[1]; pa = d_in[2]; }

  const float* x    = (const float*)px;
  const int*   wids = (const int*)pw;
  const float* A    = (const float*)pa;
  float* out = (float*)d_out;
  (void)out_size;

  const size_t need = (size_t)NS * B_TOT * R_DIM * sizeof(float);  // 8 MB (proven fits)
  if (ws_size >= need) {
    float* part = (float*)d_ws;
    k_lora_mfma<<<dim3(NA_DIM * NS), dim3(256), 0, stream>>>(x, wids, A, part);
    k_reduce16<<<dim3(128), dim3(256), 0, stream>>>(part, out);
  } else {
    k_naive_f32<<<dim3(B_TOT), dim3(256), 0, stream>>>(x, wids, A, out);
  }
}

// Round 14
// 26.260 us; speedup vs baseline: 4.0205x; 1.0582x over previous
//
#include <hip/hip_runtime.h>
#include <stdint.h>

#define B_TOT 2048
#define H_DIM 4096
#define R_DIM 64
#define NA_DIM 64
#define NS 16                    // k-slices
#define KS (H_DIM / NS)          // 256 k per slice
#define LW 132                   // X_lds row stride in u32 words, %32=4
#define X_ELEMS (B_TOT*H_DIM)
#define W_ELEMS (B_TOT)
#define A_ELEMS (NA_DIM*H_DIM*R_DIM)

typedef _Float16 f16x8 __attribute__((ext_vector_type(8)));
typedef float    f32x4 __attribute__((ext_vector_type(4)));

__device__ __forceinline__ uint32_t pkf16(float a, float b) {
  // exact: inputs are fp16-representable, RTZ == RNE == identity
  auto h = __builtin_amdgcn_cvt_pkrtz(a, b);
  union { decltype(h) v; uint32_t u; } cv; cv.v = h; return cv.u;
}

// Block (adapter a, k-slice ks): GEMM  X_a[n x 256] @ A_a[256 x 64] -> part[ks].
// A-fragments live in REGISTERS (afr[8], 32 VGPR): loaded once per block
// straight from global (strided dwords, one-time), reused across all M-groups.
// No A_lds at all -> LDS 12.6 KB -> 4 blocks/CU, whole 1024-block grid
// co-resident. X staged per 16-sample group as f16 [m][k] (identical to the
// verified round-13 kernel). Fragment (lane,elem)->k maps are IDENTICAL for
// X and A (k-permutation-safe); C/D map col=l&15 (->r), row=(l>>4)*4+i
// (->sample) drives guarded f32 stores. __launch_bounds__(256,4): VGPR cap
// 128 >= ~75 needed -- explicit anti-spill (round-11/12 lesson).
__global__ __launch_bounds__(256, 4)
void k_lora_mfma2(const float* __restrict__ x, const int* __restrict__ wids,
                  const float* __restrict__ A, float* __restrict__ part) {
  __shared__ __align__(16) uint32_t X_lds[16 * LW];     // 8.4 KB
  __shared__ uint16_t sbin[B_TOT];                      // 4 KB
  __shared__ int sn;

  const int bx = blockIdx.x;
  const int a = bx / NS, ks = bx % NS;
  const int t = threadIdx.x;
  const int w = t >> 6, l = t & 63;
  const int ml = l & 15;    // X-row / D-col lane index
  const int kg = l >> 4;    // k-group within fragment

  // ---- A-fragments -> registers (one-time; reused every M-group) ----
  // afr[kst] elem j = A[ks*256 + kst*32 + kg*8 + j][w*16 + ml]  (f32->f16 exact)
  const float* Abase = A + ((size_t)a * H_DIM + (size_t)ks * KS) * R_DIM
                         + (size_t)(w * 16 + ml);
  f16x8 afr[8];
#pragma unroll
  for (int kst = 0; kst < 8; ++kst) {
    const float* p = Abase + (size_t)(kst * 32 + kg * 8) * R_DIM;
    float v0 = p[0],   v1 = p[64],  v2 = p[128], v3 = p[192];
    float v4 = p[256], v5 = p[320], v6 = p[384], v7 = p[448];
    union { uint4 u; f16x8 h; } cv;
    cv.u.x = pkf16(v0, v1); cv.u.y = pkf16(v2, v3);
    cv.u.z = pkf16(v4, v5); cv.u.w = pkf16(v6, v7);
    afr[kst] = cv.h;
  }

  // ---- wave 0: ballot-scan wids -> ordered sample list ----
  if (w == 0) {
    int v[32];
#pragma unroll
    for (int i = 0; i < 32; ++i) v[i] = wids[i * 64 + l];
    int cnt = 0;
#pragma unroll
    for (int i = 0; i < 32; ++i) {
      bool hit = (v[i] == a);
      unsigned long long m = __ballot(hit);
      if (hit) sbin[cnt + __popcll(m & ((1ull << l) - 1ull))] = (uint16_t)(i * 64 + l);
      cnt += __popcll(m);
    }
    if (l == 0) sn = cnt;
  }
  __syncthreads();   // sbin ready
  const int n = sn;
  if (n == 0) return;

  const int m_st = t >> 4, q_st = t & 15;   // X staging roles

  for (int mg = 0; mg * 16 < n; ++mg) {
    const int base = mg * 16;
    // ---- stage x: 16 rows x 256 k f32 -> f16 [m][k] (coalesced) ----
    {
      int sidx = base + m_st; if (sidx > n - 1) sidx = n - 1;
      const float* xr = x + (size_t)sbin[sidx] * H_DIM + (size_t)ks * KS;
#pragma unroll
      for (int j = 0; j < 2; ++j) {
        const int c = q_st + j * 16;          // 8-elem chunk id
        const int k = c * 8;
        float4 u0 = *(const float4*)(xr + k);
        float4 u1 = *(const float4*)(xr + k + 4);
        uint4 pw;
        pw.x = pkf16(u0.x, u0.y); pw.y = pkf16(u0.z, u0.w);
        pw.z = pkf16(u1.x, u1.y); pw.w = pkf16(u1.z, u1.w);
        *(uint4*)&X_lds[m_st * LW + c * 4] = pw;
      }
    }
    __syncthreads();   // X ready

    // ---- 8 x mfma_f32_16x16x32_f16; A operand straight from registers ----
    f32x4 acc = {0.f, 0.f, 0.f, 0.f};
#pragma unroll
    for (int kst = 0; kst < 8; ++kst) {
      f16x8 xf = *(const f16x8*)(X_lds + ml * LW + kst * 16 + kg * 4);
      acc = __builtin_amdgcn_mfma_f32_16x16x32_f16(xf, afr[kst], acc, 0, 0, 0);
    }

    // ---- store: D col = ml (-> r = w*16+ml), row = kg*4+i (-> sample) ----
#pragma unroll
    for (int i = 0; i < 4; ++i) {
      const int sidx = base + kg * 4 + i;
      if (sidx < n) {
        part[(size_t)ks * (B_TOT * R_DIM) +
             (size_t)sbin[sidx] * R_DIM + w * 16 + ml] = acc[i];
      }
    }
    if ((mg + 1) * 16 < n) __syncthreads();   // X_lds reads done before restage
  }
}

__global__ __launch_bounds__(256)
void k_reduce16(const float* __restrict__ part, float* __restrict__ out) {
  int t = blockIdx.x * 256 + threadIdx.x;   // 32768 threads, one float4 each
  size_t o = (size_t)t * 4;
  float v0 = 0.f, v1 = 0.f, v2 = 0.f, v3 = 0.f;
#pragma unroll
  for (int p = 0; p < NS; ++p) {
    float4 q = *(const float4*)&part[(size_t)p * (B_TOT * R_DIM) + o];
    v0 += q.x; v1 += q.y; v2 += q.z; v3 += q.w;
  }
  *(float4*)&out[o] = make_float4(v0, v1, v2, v3);
}

// No-workspace fallback (proven-correct round-6 naive kernel).
__global__ __launch_bounds__(256)
void k_naive_f32(const float* __restrict__ x, const int* __restrict__ wids,
                 const float* __restrict__ A, float* __restrict__ out) {
  __shared__ float red[256];
  const int b = blockIdx.x;
  const int t = threadIdx.x;
  const int r = t & 63;
  const int q = t >> 6;
  const int a = wids[b];
  const float* xrow = x + (size_t)b * H_DIM;
  const float* Aad  = A + (size_t)a * H_DIM * R_DIM + r;
  float acc = 0.f;
  const int h0 = q * (H_DIM / 4), h1 = h0 + (H_DIM / 4);
  for (int h = h0; h < h1; ++h) acc += xrow[h] * Aad[(size_t)h * R_DIM];
  red[t] = acc;
  __syncthreads();
  if (t < 64) {
    out[(size_t)b * R_DIM + t] = red[t] + red[t + 64] + red[t + 128] + red[t + 192];
  }
}

extern "C" void kernel_launch(void* const* d_in, const int* in_sizes, int n_in,
                              void* d_out, int out_size, void* d_ws, size_t ws_size,
                              hipStream_t stream) {
  // Identify inputs by element count — robust to any ordering.
  const void* px = nullptr; const void* pw = nullptr; const void* pa = nullptr;
  for (int i = 0; i < n_in; ++i) {
    if (in_sizes[i] == X_ELEMS) px = d_in[i];
    else if (in_sizes[i] == W_ELEMS) pw = d_in[i];
    else if (in_sizes[i] == A_ELEMS) pa = d_in[i];
  }
  if (!px || !pw || !pa) { px = d_in[0]; pw = d_in[1]; pa = d_in[2]; }

  const float* x    = (const float*)px;
  const int*   wids = (const int*)pw;
  const float* A    = (const float*)pa;
  float* out = (float*)d_out;
  (void)out_size;

  const size_t need = (size_t)NS * B_TOT * R_DIM * sizeof(float);  // 8 MB (ws ~268 MB observed)
  if (ws_size >= need) {
    float* part = (float*)d_ws;
    k_lora_mfma2<<<dim3(NA_DIM * NS), dim3(256), 0, stream>>>(x, wids, A, part);
    k_reduce16<<<dim3(128), dim3(256), 0, stream>>>(part, out);
  } else {
    k_naive_f32<<<dim3(B_TOT), dim3(256), 0, stream>>>(x, wids, A, out);
  }
}

// Round 15
// 25.969 us; speedup vs baseline: 4.0655x; 1.0112x over previous
//
#include <hip/hip_runtime.h>
#include <stdint.h>

#define B_TOT 2048
#define H_DIM 4096
#define R_DIM 64
#define NA_DIM 64
#define NS 16                    // k-slices
#define KS (H_DIM / NS)          // 256 k per slice
#define LW 132                   // X_lds row stride in u32 words, %32=4
#define X_ELEMS (B_TOT*H_DIM)
#define W_ELEMS (B_TOT)
#define A_ELEMS (NA_DIM*H_DIM*R_DIM)

typedef _Float16 f16x8 __attribute__((ext_vector_type(8)));
typedef float    f32x4 __attribute__((ext_vector_type(4)));

__device__ __forceinline__ uint32_t pkf16(float a, float b) {
  // exact: inputs are fp16-representable, RTZ == RNE == identity
  auto h = __builtin_amdgcn_cvt_pkrtz(a, b);
  union { decltype(h) v; uint32_t u; } cv; cv.v = h; return cv.u;
}

// Block (adapter a = bx&63, k-slice ks = bx>>6  -- remapped so each CU's
// co-resident blocks come from DIFFERENT adapters, averaging n_a imbalance).
// GEMM X_a[n x 256] @ A_a[256 x 64] -> f16 partial slice ks.
// A-fragments in registers (afr[8], 32 VGPR), loaded once per block.
// X staged per 16-sample group as f16 [m][k]. Fragment (lane,elem)->k maps
// identical for X and A (k-permutation-safe). C/D: col=l&15 (->r),
// row=(l>>4)*4+i (->sample). Partials stored f16 (error ~1e-3 << thr 0.11).
__global__ __launch_bounds__(256, 4)
void k_lora_mfma3(const float* __restrict__ x, const int* __restrict__ wids,
                  const float* __restrict__ A, uint16_t* __restrict__ part) {
  __shared__ __align__(16) uint32_t X_lds[16 * LW];     // 8.4 KB
  __shared__ uint16_t sbin[B_TOT];                      // 4 KB
  __shared__ int sn;

  const int bx = blockIdx.x;
  const int a = bx & 63, ks = bx >> 6;
  const int t = threadIdx.x;
  const int w = t >> 6, l = t & 63;
  const int ml = l & 15;    // X-row / D-col lane index
  const int kg = l >> 4;    // k-group within fragment

  // ---- A-fragments -> registers (one-time; reused every M-group) ----
  const float* Abase = A + ((size_t)a * H_DIM + (size_t)ks * KS) * R_DIM
                         + (size_t)(w * 16 + ml);
  f16x8 afr[8];
#pragma unroll
  for (int kst = 0; kst < 8; ++kst) {
    const float* p = Abase + (size_t)(kst * 32 + kg * 8) * R_DIM;
    float v0 = p[0],   v1 = p[64],  v2 = p[128], v3 = p[192];
    float v4 = p[256], v5 = p[320], v6 = p[384], v7 = p[448];
    union { uint4 u; f16x8 h; } cv;
    cv.u.x = pkf16(v0, v1); cv.u.y = pkf16(v2, v3);
    cv.u.z = pkf16(v4, v5); cv.u.w = pkf16(v6, v7);
    afr[kst] = cv.h;
  }

  // ---- wave 0: ballot-scan wids -> ordered sample list ----
  if (w == 0) {
    int v[32];
#pragma unroll
    for (int i = 0; i < 32; ++i) v[i] = wids[i * 64 + l];
    int cnt = 0;
#pragma unroll
    for (int i = 0; i < 32; ++i) {
      bool hit = (v[i] == a);
      unsigned long long m = __ballot(hit);
      if (hit) sbin[cnt + __popcll(m & ((1ull << l) - 1ull))] = (uint16_t)(i * 64 + l);
      cnt += __popcll(m);
    }
    if (l == 0) sn = cnt;
  }
  __syncthreads();   // sbin ready
  const int n = sn;
  if (n == 0) return;

  const int m_st = t >> 4, q_st = t & 15;   // X staging roles

  for (int mg = 0; mg * 16 < n; ++mg) {
    const int base = mg * 16;
    // ---- stage x: 16 rows x 256 k f32 -> f16 [m][k] (coalesced) ----
    {
      int sidx = base + m_st; if (sidx > n - 1) sidx = n - 1;
      const float* xr = x + (size_t)sbin[sidx] * H_DIM + (size_t)ks * KS;
#pragma unroll
      for (int j = 0; j < 2; ++j) {
        const int c = q_st + j * 16;          // 8-elem chunk id
        const int k = c * 8;
        float4 u0 = *(const float4*)(xr + k);
        float4 u1 = *(const float4*)(xr + k + 4);
        uint4 pw;
        pw.x = pkf16(u0.x, u0.y); pw.y = pkf16(u0.z, u0.w);
        pw.z = pkf16(u1.x, u1.y); pw.w = pkf16(u1.z, u1.w);
        *(uint4*)&X_lds[m_st * LW + c * 4] = pw;
      }
    }
    __syncthreads();   // X ready

    // ---- 8 x mfma_f32_16x16x32_f16; A operand straight from registers ----
    f32x4 acc = {0.f, 0.f, 0.f, 0.f};
#pragma unroll
    for (int kst = 0; kst < 8; ++kst) {
      f16x8 xf = *(const f16x8*)(X_lds + ml * LW + kst * 16 + kg * 4);
      acc = __builtin_amdgcn_mfma_f32_16x16x32_f16(xf, afr[kst], acc, 0, 0, 0);
    }

    // ---- store f16 partial: col=ml (->r=w*16+ml), row=kg*4+i (->sample) ----
#pragma unroll
    for (int i = 0; i < 4; ++i) {
      const int sidx = base + kg * 4 + i;
      if (sidx < n) {
        union { _Float16 h; uint16_t u; } cv; cv.h = (_Float16)acc[i];
        part[(size_t)ks * (B_TOT * R_DIM) +
             (size_t)sbin[sidx] * R_DIM + w * 16 + ml] = cv.u;
      }
    }
    if ((mg + 1) * 16 < n) __syncthreads();   // X_lds reads done before restage
  }
}

__global__ __launch_bounds__(256)
void k_reduce16h(const uint16_t* __restrict__ part, float* __restrict__ out) {
  const int t = blockIdx.x * 256 + threadIdx.x;   // 32768 threads: (b, r-quad)
  const int b = t >> 4, r4 = t & 15;
  const size_t o = (size_t)b * R_DIM + r4 * 4;
  float v0 = 0.f, v1 = 0.f, v2 = 0.f, v3 = 0.f;
#pragma unroll
  for (int p = 0; p < NS; ++p) {
    uint2 q = *(const uint2*)&part[(size_t)p * (B_TOT * R_DIM) + o];
    union { uint32_t u; _Float16 h[2]; } c0, c1;
    c0.u = q.x; c1.u = q.y;
    v0 += (float)c0.h[0]; v1 += (float)c0.h[1];
    v2 += (float)c1.h[0]; v3 += (float)c1.h[1];
  }
  *(float4*)&out[o] = make_float4(v0, v1, v2, v3);
}

// No-workspace fallback (proven-correct round-6 naive kernel).
__global__ __launch_bounds__(256)
void k_naive_f32(const float* __restrict__ x, const int* __restrict__ wids,
                 const float* __restrict__ A, float* __restrict__ out) {
  __shared__ float red[256];
  const int b = blockIdx.x;
  const int t = threadIdx.x;
  const int r = t & 63;
  const int q = t >> 6;
  const int a = wids[b];
  const float* xrow = x + (size_t)b * H_DIM;
  const float* Aad  = A + (size_t)a * H_DIM * R_DIM + r;
  float acc = 0.f;
  const int h0 = q * (H_DIM / 4), h1 = h0 + (H_DIM / 4);
  for (int h = h0; h < h1; ++h) acc += xrow[h] * Aad[(size_t)h * R_DIM];
  red[t] = acc;
  __syncthreads();
  if (t < 64) {
    out[(size_t)b * R_DIM + t] = red[t] + red[t + 64] + red[t + 128] + red[t + 192];
  }
}

extern "C" void kernel_launch(void* const* d_in, const int* in_sizes, int n_in,
                              void* d_out, int out_size, void* d_ws, size_t ws_size,
                              hipStream_t stream) {
  // Identify inputs by element count — robust to any ordering.
  const void* px = nullptr; const void* pw = nullptr; const void* pa = nullptr;
  for (int i = 0; i < n_in; ++i) {
    if (in_sizes[i] == X_ELEMS) px = d_in[i];
    else if (in_sizes[i] == W_ELEMS) pw = d_in[i];
    else if (in_sizes[i] == A_ELEMS) pa = d_in[i];
  }
  if (!px || !pw || !pa) { px = d_in[0]; pw = d_in[1]; pa = d_in[2]; }

  const float* x    = (const float*)px;
  const int*   wids = (const int*)pw;
  const float* A    = (const float*)pa;
  float* out = (float*)d_out;
  (void)out_size;

  const size_t need = (size_t)NS * B_TOT * R_DIM * sizeof(uint16_t);  // 4 MB (ws ~268 MB observed)
  if (ws_size >= need) {
    uint16_t* part = (uint16_t*)d_ws;
    k_lora_mfma3<<<dim3(NA_DIM * NS), dim3(256), 0, stream>>>(x, wids, A, part);
    k_reduce16h<<<dim3(128), dim3(256), 0, stream>>>(part, out);
  } else {
    k_naive_f32<<<dim3(B_TOT), dim3(256), 0, stream>>>(x, wids, A, out);
  }
}